// Round 1
// baseline (407.664 us; speedup 1.0000x reference)
//
#include <hip/hip_runtime.h>
#include <math.h>

#define LMAX  32768
#define WWIN  1024
#define KFIR  128
#define CHUNK 1024
#define HALO  128
#define SEGN  (CHUNK + HALO)   // 1152

// ---------------- per-note parameter kernel ----------------
__global__ __launch_bounds__(256) void params_k(
    const float* __restrict__ freq, const float* __restrict__ velo,
    const float* __restrict__ w1,  const float* __restrict__ b1,
    const float* __restrict__ w2,  const float* __restrict__ b2,
    const float* __restrict__ ws1, const float* __restrict__ bs1,
    const float* __restrict__ ws2, const float* __restrict__ bs2,
    const int* __restrict__ starts, const int* __restrict__ lengths,
    int Dn, int N,
    float* __restrict__ amps_out, int* __restrict__ outlen_out,
    float* __restrict__ veln_out)
{
    int n = blockIdx.x * blockDim.x + threadIdx.x;
    if (n >= N) return;
    int st  = starts[n];
    int len = lengths[n];
    int ol  = min(st + len, Dn) - st;
    ol = max(0, min(ol, LMAX));
    outlen_out[n] = ol;

    float v = velo[n] * (1.0f / 127.0f);
    veln_out[n] = v;

    float nt = (float)st / (float)Dn;

    // time latent: 1 -> 32 -> 2
    float lat0 = b2[0], lat1 = b2[1];
    #pragma unroll
    for (int j = 0; j < 32; ++j) {
        float h = fmaxf(fmaf(nt, w1[j], b1[j]), 0.0f);
        lat0 = fmaf(h, w2[j * 2 + 0], lat0);
        lat1 = fmaf(h, w2[j * 2 + 1], lat1);
    }

    float feat0 = freq[n], feat1 = v, feat2 = lat0, feat3 = lat1;

    // synth MLP: 4 -> 64 -> 8, softplus
    float hid[64];
    #pragma unroll
    for (int j = 0; j < 64; ++j) {
        float a = bs1[j];
        a = fmaf(feat0, ws1[0 * 64 + j], a);
        a = fmaf(feat1, ws1[1 * 64 + j], a);
        a = fmaf(feat2, ws1[2 * 64 + j], a);
        a = fmaf(feat3, ws1[3 * 64 + j], a);
        hid[j] = fmaxf(a, 0.0f);
    }
    #pragma unroll
    for (int h = 0; h < 8; ++h) {
        float a = bs2[h];
        for (int j = 0; j < 64; ++j) a = fmaf(hid[j], ws2[j * 8 + h], a);
        // numerically-stable softplus, matches jax.nn.softplus
        float sp = fmaxf(a, 0.0f) + log1pf(expf(-fabsf(a)));
        amps_out[n * 8 + h] = sp;
    }
}

// ---------------- main synthesis kernel ----------------
// grid: (LMAX/CHUNK, N); block 256; each thread -> 4 consecutive outputs
__global__ __launch_bounds__(256) void synth_k(
    const float* __restrict__ freq_g, const int* __restrict__ starts,
    const float* __restrict__ amps_g, const int* __restrict__ outlen_g,
    const float* __restrict__ veln_g, const float* __restrict__ fir,
    float* __restrict__ out, int Dn)
{
    __shared__ __align__(16) float seg[SEGN];

    const int note = blockIdx.y;
    const int ol   = outlen_g[note];
    const int c0   = blockIdx.x * CHUNK;
    if (c0 >= ol) return;                    // uniform early exit

    const float f = freq_g[note];
    const float v = veln_g[note];
    const float* an = amps_g + note * 8;
    const float A0 = an[0], A1 = an[1], A2 = an[2], A3 = an[3];
    const float A4 = an[4], A5 = an[5], A6 = an[6], A7 = an[7];

    const int tid = threadIdx.x;
    const double inv2pi = 0.15915494309189535;
    const double fd = (double)f;

    // ---- stage windowed/masked segment (with 128-sample halo) into LDS ----
    for (int x = tid; x < SEGN; x += 256) {
        int t = c0 - HALO + x;
        float val = 0.0f;
        if (t >= 0 && t < ol) {
            // phase mod 2pi, reduced in double => exact for all integer harmonics
            double rev = fd * (double)t * inv2pi;
            float r = (float)(rev - floor(rev));          // [0,1) revolutions
            float s1 = __builtin_amdgcn_sinf(r);          // sin(2*pi*r) = sin(theta)
            float c1 = __builtin_amdgcn_cosf(r);
            float tc = c1 + c1;
            // Chebyshev: sin((h+1)t) = 2cos(t) sin(ht) - sin((h-1)t)
            float sA = s1;
            float sum = A0 * sA;
            float sB = tc * sA;
            sum = fmaf(A1, sB, sum);
            float sC = fmaf(tc, sB, -sA); sum = fmaf(A2, sC, sum);
            float sD = fmaf(tc, sC, -sB); sum = fmaf(A3, sD, sum);
            float sE = fmaf(tc, sD, -sC); sum = fmaf(A4, sE, sum);
            float sF = fmaf(tc, sE, -sD); sum = fmaf(A5, sF, sum);
            float sG = fmaf(tc, sF, -sE); sum = fmaf(A6, sG, sum);
            float sH = fmaf(tc, sG, -sF); sum = fmaf(A7, sH, sum);
            // hann window on last WWIN samples: 0.5*(1-cos(2*pi*wpos/WWIN))
            int wpos = t - (ol - WWIN);
            float factor = 1.0f;
            if (wpos >= 0)
                factor = 0.5f - 0.5f * __builtin_amdgcn_cosf((float)wpos * (1.0f / WWIN));
            val = v * sum * factor;
        }
        seg[x] = val;
    }
    __syncthreads();

    // ---- 128-tap causal FIR, 4 outputs/thread, sliding register window ----
    // y[i] = sum_k fir[k] * seg[i + k - 127]  (JAX cross-correlation w/ left pad)
    const int a = tid * 4;                   // LDS base (16B aligned)
    const int iloc = c0 + a;                 // note-local index of first output

    float w0, w1r, w2r, w3r, w4r, w5r, w6r, w7r;
    {
        float4 cur = *(const float4*)&seg[a];
        w0 = cur.x; w1r = cur.y; w2r = cur.z; w3r = cur.w;
    }
    float acc0 = 0.0f, acc1 = 0.0f, acc2 = 0.0f, acc3 = 0.0f;
    #pragma unroll
    for (int m = 0; m < 32; ++m) {
        float4 nxt = *(const float4*)&seg[a + 4 * m + 4];
        w4r = nxt.x; w5r = nxt.y; w6r = nxt.z; w7r = nxt.w;
        float t0 = fir[4 * m + 0];           // block-uniform -> s_load
        float t1 = fir[4 * m + 1];
        float t2 = fir[4 * m + 2];
        float t3 = fir[4 * m + 3];
        acc0 = fmaf(t0, w1r, acc0); acc1 = fmaf(t0, w2r, acc1);
        acc2 = fmaf(t0, w3r, acc2); acc3 = fmaf(t0, w4r, acc3);
        acc0 = fmaf(t1, w2r, acc0); acc1 = fmaf(t1, w3r, acc1);
        acc2 = fmaf(t1, w4r, acc2); acc3 = fmaf(t1, w5r, acc3);
        acc0 = fmaf(t2, w3r, acc0); acc1 = fmaf(t2, w4r, acc1);
        acc2 = fmaf(t2, w5r, acc2); acc3 = fmaf(t2, w6r, acc3);
        acc0 = fmaf(t3, w4r, acc0); acc1 = fmaf(t3, w5r, acc1);
        acc2 = fmaf(t3, w6r, acc2); acc3 = fmaf(t3, w7r, acc3);
        w0 = w4r; w1r = w5r; w2r = w6r; w3r = w7r;
    }
    (void)w0;

    // ---- tanh + scatter (overlap-add) ----
    const int gbase = starts[note] + iloc;
    if (iloc + 0 < ol && gbase + 0 < Dn) atomicAdd(&out[gbase + 0], tanhf(acc0));
    if (iloc + 1 < ol && gbase + 1 < Dn) atomicAdd(&out[gbase + 1], tanhf(acc1));
    if (iloc + 2 < ol && gbase + 2 < Dn) atomicAdd(&out[gbase + 2], tanhf(acc2));
    if (iloc + 3 < ol && gbase + 3 < Dn) atomicAdd(&out[gbase + 3], tanhf(acc3));
}

// ---------------- launcher ----------------
extern "C" void kernel_launch(void* const* d_in, const int* in_sizes, int n_in,
                              void* d_out, int out_size, void* d_ws, size_t ws_size,
                              hipStream_t stream) {
    const float* freq    = (const float*)d_in[0];
    const float* velo    = (const float*)d_in[1];
    const float* w1      = (const float*)d_in[2];
    const float* b1      = (const float*)d_in[3];
    const float* w2      = (const float*)d_in[4];
    const float* b2      = (const float*)d_in[5];
    const float* ws1     = (const float*)d_in[6];
    const float* bs1     = (const float*)d_in[7];
    const float* ws2     = (const float*)d_in[8];
    const float* bs2     = (const float*)d_in[9];
    const float* fir     = (const float*)d_in[10];
    const int*   starts  = (const int*)d_in[11];
    const int*   lengths = (const int*)d_in[12];

    const int N  = in_sizes[0];
    const int Dn = out_size;
    float* out = (float*)d_out;

    // workspace layout: amps[N*8] | outlen[N] | veln[N]
    float* amps   = (float*)d_ws;
    int*   outlen = (int*)((char*)d_ws + (size_t)N * 8 * sizeof(float));
    float* veln   = (float*)((char*)d_ws + (size_t)N * 8 * sizeof(float) + (size_t)N * sizeof(int));

    hipMemsetAsync(d_out, 0, (size_t)Dn * sizeof(float), stream);

    params_k<<<(N + 255) / 256, 256, 0, stream>>>(
        freq, velo, w1, b1, w2, b2, ws1, bs1, ws2, bs2,
        starts, lengths, Dn, N, amps, outlen, veln);

    dim3 grid(LMAX / CHUNK, N);
    synth_k<<<grid, 256, 0, stream>>>(
        freq, starts, amps, outlen, veln, fir, out, Dn);
}

// Round 2
// 364.151 us; speedup vs baseline: 1.1195x; 1.1195x over previous
//
#include <hip/hip_runtime.h>
#include <math.h>

#define LMAX  32768
#define WWIN  1024
#define KFIR  128
#define TO    1024               // outputs per block (tile)
#define HALO  128
#define SEGN  (TO + HALO)        // 1152 staged synth samples
#define NMAX  1024               // max notes

// ---------------- per-note parameter kernel ----------------
__global__ __launch_bounds__(256) void params_k(
    const float* __restrict__ freq, const float* __restrict__ velo,
    const float* __restrict__ w1,  const float* __restrict__ b1,
    const float* __restrict__ w2,  const float* __restrict__ b2,
    const float* __restrict__ ws1, const float* __restrict__ bs1,
    const float* __restrict__ ws2, const float* __restrict__ bs2,
    const int* __restrict__ starts, const int* __restrict__ lengths,
    int Dn, int N,
    float* __restrict__ amps_out, int* __restrict__ outlen_out,
    float* __restrict__ veln_out)
{
    int n = blockIdx.x * blockDim.x + threadIdx.x;
    if (n >= N) return;
    int st  = starts[n];
    int len = lengths[n];
    int ol  = min(st + len, Dn) - st;
    ol = max(0, min(ol, LMAX));
    outlen_out[n] = ol;

    float v = velo[n] * (1.0f / 127.0f);
    veln_out[n] = v;

    float nt = (float)st / (float)Dn;

    // time latent: 1 -> 32 -> 2
    float lat0 = b2[0], lat1 = b2[1];
    #pragma unroll
    for (int j = 0; j < 32; ++j) {
        float h = fmaxf(fmaf(nt, w1[j], b1[j]), 0.0f);
        lat0 = fmaf(h, w2[j * 2 + 0], lat0);
        lat1 = fmaf(h, w2[j * 2 + 1], lat1);
    }

    float feat0 = freq[n], feat1 = v, feat2 = lat0, feat3 = lat1;

    // synth MLP: 4 -> 64 -> 8, softplus
    float hid[64];
    #pragma unroll
    for (int j = 0; j < 64; ++j) {
        float a = bs1[j];
        a = fmaf(feat0, ws1[0 * 64 + j], a);
        a = fmaf(feat1, ws1[1 * 64 + j], a);
        a = fmaf(feat2, ws1[2 * 64 + j], a);
        a = fmaf(feat3, ws1[3 * 64 + j], a);
        hid[j] = fmaxf(a, 0.0f);
    }
    #pragma unroll
    for (int h = 0; h < 8; ++h) {
        float a = bs2[h];
        for (int j = 0; j < 64; ++j) a = fmaf(hid[j], ws2[j * 8 + h], a);
        float sp = fmaxf(a, 0.0f) + log1pf(expf(-fabsf(a)));
        amps_out[n * 8 + h] = sp;
    }
}

// ---------------- gather synthesis kernel ----------------
// grid: ceil(Dn/TO) blocks, 256 threads; each thread owns 4 consecutive outputs.
__global__ __launch_bounds__(256) void synth_gather_k(
    const float* __restrict__ freq_g, const int* __restrict__ starts,
    const float* __restrict__ amps_g, const int* __restrict__ outlen_g,
    const float* __restrict__ veln_g, const float* __restrict__ fir,
    float* __restrict__ out, int Dn, int N)
{
    __shared__ __align__(16) float seg[SEGN];
    __shared__ int note_list[NMAX];
    __shared__ int note_cnt;

    const int tid = threadIdx.x;
    const int o0  = blockIdx.x * TO;          // first output of this tile
    const int o_end = min(o0 + TO, Dn);

    // ---- build list of notes covering [o0, o_end) ----
    if (tid == 0) note_cnt = 0;
    __syncthreads();
    for (int j = tid; j < N; j += 256) {
        int st = starts[j];
        int ol = outlen_g[j];
        if (st < o_end && st + ol > o0) {
            int p = atomicAdd(&note_cnt, 1);
            note_list[p] = j;
        }
    }
    __syncthreads();
    const int K = note_cnt;

    const int a = tid * 4;                    // per-thread LDS base / tile-local output
    float acc0 = 0.0f, acc1 = 0.0f, acc2 = 0.0f, acc3 = 0.0f;

    const double inv2pi = 0.15915494309189535;

    for (int kk = 0; kk < K; ++kk) {
        const int nid = note_list[kk];
        const int st  = starts[nid];
        const int ol  = outlen_g[nid];
        const float f = freq_g[nid];
        const float v = veln_g[nid];
        const float* an = amps_g + nid * 8;
        const float A0 = an[0], A1 = an[1], A2 = an[2], A3 = an[3];
        const float A4 = an[4], A5 = an[5], A6 = an[6], A7 = an[7];
        const int base = o0 - st;             // note-local index of first tile output
        const double fd = (double)f;

        __syncthreads();                      // protect seg from previous iteration
        // ---- stage synth+window samples t = base-128+x, x in [0,SEGN) ----
        for (int x = tid; x < SEGN; x += 256) {
            int t = base - HALO + x;
            float val = 0.0f;
            if (t >= 0 && t < ol) {
                double rev = fd * (double)t * inv2pi;
                float r = (float)(rev - floor(rev));      // [0,1) revolutions
                float s1 = __builtin_amdgcn_sinf(r);
                float c1 = __builtin_amdgcn_cosf(r);
                float tc = c1 + c1;
                float sA = s1;
                float sum = A0 * sA;
                float sB = tc * sA;              sum = fmaf(A1, sB, sum);
                float sC = fmaf(tc, sB, -sA);    sum = fmaf(A2, sC, sum);
                float sD = fmaf(tc, sC, -sB);    sum = fmaf(A3, sD, sum);
                float sE = fmaf(tc, sD, -sC);    sum = fmaf(A4, sE, sum);
                float sF = fmaf(tc, sE, -sD);    sum = fmaf(A5, sF, sum);
                float sG = fmaf(tc, sF, -sE);    sum = fmaf(A6, sG, sum);
                float sH = fmaf(tc, sG, -sF);    sum = fmaf(A7, sH, sum);
                int wpos = t - (ol - WWIN);
                float factor = 1.0f;
                if (wpos >= 0)
                    factor = 0.5f - 0.5f * __builtin_amdgcn_cosf((float)wpos * (1.0f / WWIN));
                val = v * sum * factor;
            }
            seg[x] = val;
        }
        __syncthreads();

        // ---- 128-tap FIR, 4 outputs/thread, sliding register window ----
        float w1r, w2r, w3r, w4r, w5r, w6r, w7r;
        {
            float4 cur = *(const float4*)&seg[a];
            w1r = cur.y; w2r = cur.z; w3r = cur.w;   // cur.x (=seg[a]) unused: tap0 is seg[a+1]
        }
        float y0 = 0.0f, y1 = 0.0f, y2 = 0.0f, y3 = 0.0f;
        #pragma unroll
        for (int m = 0; m < 32; ++m) {
            float4 nxt = *(const float4*)&seg[a + 4 * m + 4];
            w4r = nxt.x; w5r = nxt.y; w6r = nxt.z; w7r = nxt.w;
            float t0 = fir[4 * m + 0];
            float t1 = fir[4 * m + 1];
            float t2 = fir[4 * m + 2];
            float t3 = fir[4 * m + 3];
            y0 = fmaf(t0, w1r, y0); y1 = fmaf(t0, w2r, y1);
            y2 = fmaf(t0, w3r, y2); y3 = fmaf(t0, w4r, y3);
            y0 = fmaf(t1, w2r, y0); y1 = fmaf(t1, w3r, y1);
            y2 = fmaf(t1, w4r, y2); y3 = fmaf(t1, w5r, y3);
            y0 = fmaf(t2, w3r, y0); y1 = fmaf(t2, w4r, y1);
            y2 = fmaf(t2, w5r, y2); y3 = fmaf(t2, w6r, y3);
            y0 = fmaf(t3, w4r, y0); y1 = fmaf(t3, w5r, y1);
            y2 = fmaf(t3, w6r, y2); y3 = fmaf(t3, w7r, y3);
            w1r = w5r; w2r = w6r; w3r = w7r;
        }

        // ---- tanh + masked accumulate (register, no atomics) ----
        int t_out = base + a;                 // note-local index of output a
        if (t_out + 0 >= 0 && t_out + 0 < ol) acc0 += tanhf(y0);
        if (t_out + 1 >= 0 && t_out + 1 < ol) acc1 += tanhf(y1);
        if (t_out + 2 >= 0 && t_out + 2 < ol) acc2 += tanhf(y2);
        if (t_out + 3 >= 0 && t_out + 3 < ol) acc3 += tanhf(y3);
    }

    // ---- single coalesced store per output ----
    const int o = o0 + a;
    if (o + 3 < Dn) {
        *(float4*)&out[o] = make_float4(acc0, acc1, acc2, acc3);
    } else {
        if (o + 0 < Dn) out[o + 0] = acc0;
        if (o + 1 < Dn) out[o + 1] = acc1;
        if (o + 2 < Dn) out[o + 2] = acc2;
        if (o + 3 < Dn) out[o + 3] = acc3;
    }
}

// ---------------- launcher ----------------
extern "C" void kernel_launch(void* const* d_in, const int* in_sizes, int n_in,
                              void* d_out, int out_size, void* d_ws, size_t ws_size,
                              hipStream_t stream) {
    const float* freq    = (const float*)d_in[0];
    const float* velo    = (const float*)d_in[1];
    const float* w1      = (const float*)d_in[2];
    const float* b1      = (const float*)d_in[3];
    const float* w2      = (const float*)d_in[4];
    const float* b2      = (const float*)d_in[5];
    const float* ws1     = (const float*)d_in[6];
    const float* bs1     = (const float*)d_in[7];
    const float* ws2     = (const float*)d_in[8];
    const float* bs2     = (const float*)d_in[9];
    const float* fir     = (const float*)d_in[10];
    const int*   starts  = (const int*)d_in[11];
    const int*   lengths = (const int*)d_in[12];

    const int N  = in_sizes[0];
    const int Dn = out_size;
    float* out = (float*)d_out;

    // workspace layout: amps[N*8] | outlen[N] | veln[N]
    float* amps   = (float*)d_ws;
    int*   outlen = (int*)((char*)d_ws + (size_t)N * 8 * sizeof(float));
    float* veln   = (float*)((char*)d_ws + (size_t)N * 8 * sizeof(float) + (size_t)N * sizeof(int));

    params_k<<<(N + 255) / 256, 256, 0, stream>>>(
        freq, velo, w1, b1, w2, b2, ws1, bs1, ws2, bs2,
        starts, lengths, Dn, N, amps, outlen, veln);

    int n_tiles = (Dn + TO - 1) / TO;
    synth_gather_k<<<n_tiles, 256, 0, stream>>>(
        freq, starts, amps, outlen, veln, fir, out, Dn, N);
}

// Round 3
// 288.806 us; speedup vs baseline: 1.4115x; 1.2609x over previous
//
#include <hip/hip_runtime.h>
#include <math.h>

#define LMAX  32768
#define WWIN  1024
#define KFIR  128
#define TO    1024               // outputs per block (tile)
#define HALO  128
#define SEGN  (TO + HALO)        // 1152 staged synth samples
#define NMAX  1024               // max notes

// ---------------- per-note parameter kernel ----------------
__global__ __launch_bounds__(256) void params_k(
    const float* __restrict__ freq, const float* __restrict__ velo,
    const float* __restrict__ w1,  const float* __restrict__ b1,
    const float* __restrict__ w2,  const float* __restrict__ b2,
    const float* __restrict__ ws1, const float* __restrict__ bs1,
    const float* __restrict__ ws2, const float* __restrict__ bs2,
    const int* __restrict__ starts, const int* __restrict__ lengths,
    int Dn, int N,
    float* __restrict__ amps_out, int* __restrict__ outlen_out,
    float* __restrict__ veln_out)
{
    int n = blockIdx.x * blockDim.x + threadIdx.x;
    if (n >= N) return;
    int st  = starts[n];
    int len = lengths[n];
    int ol  = min(st + len, Dn) - st;
    ol = max(0, min(ol, LMAX));
    outlen_out[n] = ol;

    float v = velo[n] * (1.0f / 127.0f);
    veln_out[n] = v;

    float nt = (float)st / (float)Dn;

    // time latent: 1 -> 32 -> 2
    float lat0 = b2[0], lat1 = b2[1];
    #pragma unroll
    for (int j = 0; j < 32; ++j) {
        float h = fmaxf(fmaf(nt, w1[j], b1[j]), 0.0f);
        lat0 = fmaf(h, w2[j * 2 + 0], lat0);
        lat1 = fmaf(h, w2[j * 2 + 1], lat1);
    }

    float feat0 = freq[n], feat1 = v, feat2 = lat0, feat3 = lat1;

    // synth MLP: 4 -> 64 -> 8, softplus
    float hid[64];
    #pragma unroll
    for (int j = 0; j < 64; ++j) {
        float a = bs1[j];
        a = fmaf(feat0, ws1[0 * 64 + j], a);
        a = fmaf(feat1, ws1[1 * 64 + j], a);
        a = fmaf(feat2, ws1[2 * 64 + j], a);
        a = fmaf(feat3, ws1[3 * 64 + j], a);
        hid[j] = fmaxf(a, 0.0f);
    }
    #pragma unroll
    for (int h = 0; h < 8; ++h) {
        float a = bs2[h];
        for (int j = 0; j < 64; ++j) a = fmaf(hid[j], ws2[j * 8 + h], a);
        float sp = fmaxf(a, 0.0f) + log1pf(expf(-fabsf(a)));
        amps_out[n * 8 + h] = sp;
    }
}

__device__ __forceinline__ float fast_tanh(float x) {
    // tanh(x) = 1 - 2/(exp(2x)+1); exp via v_exp_f32 (exp2)
    float e = __builtin_amdgcn_exp2f(x * 2.8853900817779268f);  // 2*log2(e)
    return fmaf(-2.0f, __builtin_amdgcn_rcpf(e + 1.0f), 1.0f);
}

// ---------------- gather synthesis kernel ----------------
// grid: ceil(Dn/TO) blocks, 256 threads; each thread owns 4 consecutive outputs.
__global__ __launch_bounds__(256, 4) void synth_gather_k(
    const float* __restrict__ freq_g, const int* __restrict__ starts,
    const float* __restrict__ amps_g, const int* __restrict__ outlen_g,
    const float* __restrict__ veln_g, const float* __restrict__ fir,
    float* __restrict__ out, int Dn, int N)
{
    __shared__ __align__(16) float seg[SEGN];
    __shared__ __align__(16) float fir_s[KFIR];
    __shared__ int note_list[NMAX];
    __shared__ int note_cnt;

    const int tid = threadIdx.x;
    const int o0  = blockIdx.x * TO;          // first output of this tile
    const int o_end = min(o0 + TO, Dn);

    // ---- stage FIR taps into LDS (once per block) ----
    if (tid < KFIR) fir_s[tid] = fir[tid];

    // ---- build list of notes covering [o0, o_end) ----
    if (tid == 0) note_cnt = 0;
    __syncthreads();
    for (int j = tid; j < N; j += 256) {
        int st = starts[j];
        int ol = outlen_g[j];
        if (st < o_end && st + ol > o0) {
            int p = atomicAdd(&note_cnt, 1);
            note_list[p] = j;
        }
    }
    __syncthreads();
    const int K = note_cnt;

    const int a = tid * 4;                    // per-thread LDS base / tile-local output
    float acc0 = 0.0f, acc1 = 0.0f, acc2 = 0.0f, acc3 = 0.0f;

    const double inv2pi = 0.15915494309189535;

    for (int kk = 0; kk < K; ++kk) {
        const int nid = __builtin_amdgcn_readfirstlane(note_list[kk]);
        const int st  = starts[nid];
        const int ol  = outlen_g[nid];
        const float f = freq_g[nid];
        const float v = veln_g[nid];
        const float* an = amps_g + nid * 8;
        const float A0 = an[0], A1 = an[1], A2 = an[2], A3 = an[3];
        const float A4 = an[4], A5 = an[5], A6 = an[6], A7 = an[7];
        const int base = o0 - st;             // note-local index of first tile output
        const double fd = (double)f;

        // per-thread phase seed (one f64 reduction per pair), then fp32 stepping
        const int t0 = base - HALO + tid;
        double rev0 = fd * (double)t0 * inv2pi;
        float r = (float)(rev0 - floor(rev0));            // [0,1) revolutions
        double s256d = fd * 256.0 * inv2pi;
        const float s256 = (float)(s256d - floor(s256d)); // frac(step per 256 samples)
        const int wbase = ol - WWIN;

        __syncthreads();                      // protect seg from previous iteration
        // ---- stage synth+window samples t = base-128+x, x in [0,SEGN) ----
        for (int x = tid; x < SEGN; x += 256) {
            int t = base - HALO + x;
            float val = 0.0f;
            if (t >= 0 && t < ol) {
                float s1 = __builtin_amdgcn_sinf(r);
                float c1 = __builtin_amdgcn_cosf(r);
                float tc = c1 + c1;
                float sA = s1;
                float sum = A0 * sA;
                float sB = tc * sA;              sum = fmaf(A1, sB, sum);
                float sC = fmaf(tc, sB, -sA);    sum = fmaf(A2, sC, sum);
                float sD = fmaf(tc, sC, -sB);    sum = fmaf(A3, sD, sum);
                float sE = fmaf(tc, sD, -sC);    sum = fmaf(A4, sE, sum);
                float sF = fmaf(tc, sE, -sD);    sum = fmaf(A5, sF, sum);
                float sG = fmaf(tc, sF, -sE);    sum = fmaf(A6, sG, sum);
                float sH = fmaf(tc, sG, -sF);    sum = fmaf(A7, sH, sum);
                int wpos = t - wbase;
                float factor = 1.0f;
                if (wpos >= 0)
                    factor = 0.5f - 0.5f * __builtin_amdgcn_cosf((float)wpos * (1.0f / WWIN));
                val = v * sum * factor;
            }
            seg[x] = val;
            r += s256;
            r -= (r >= 1.0f) ? 1.0f : 0.0f;
        }
        __syncthreads();

        // ---- 128-tap FIR, 4 outputs/thread, sliding register window ----
        const int t_out = base + a;           // note-local index of output a
        if (t_out + 3 >= 0 && t_out < ol) {   // skip if all 4 outputs outside note
            float w1r, w2r, w3r, w4r, w5r, w6r, w7r;
            {
                float4 cur = *(const float4*)&seg[a];
                w1r = cur.y; w2r = cur.z; w3r = cur.w;
            }
            float y0 = 0.0f, y1 = 0.0f, y2 = 0.0f, y3 = 0.0f;
            #pragma unroll
            for (int m = 0; m < 32; ++m) {
                float4 tv  = *(const float4*)&fir_s[4 * m];       // uniform broadcast
                float4 nxt = *(const float4*)&seg[a + 4 * m + 4]; // contiguous b128
                w4r = nxt.x; w5r = nxt.y; w6r = nxt.z; w7r = nxt.w;
                y0 = fmaf(tv.x, w1r, y0); y1 = fmaf(tv.x, w2r, y1);
                y2 = fmaf(tv.x, w3r, y2); y3 = fmaf(tv.x, w4r, y3);
                y0 = fmaf(tv.y, w2r, y0); y1 = fmaf(tv.y, w3r, y1);
                y2 = fmaf(tv.y, w4r, y2); y3 = fmaf(tv.y, w5r, y3);
                y0 = fmaf(tv.z, w3r, y0); y1 = fmaf(tv.z, w4r, y1);
                y2 = fmaf(tv.z, w5r, y2); y3 = fmaf(tv.z, w6r, y3);
                y0 = fmaf(tv.w, w4r, y0); y1 = fmaf(tv.w, w5r, y1);
                y2 = fmaf(tv.w, w6r, y2); y3 = fmaf(tv.w, w7r, y3);
                w1r = w5r; w2r = w6r; w3r = w7r;
            }

            // ---- tanh + masked accumulate (register, no atomics) ----
            if (t_out + 0 >= 0 && t_out + 0 < ol) acc0 += fast_tanh(y0);
            if (t_out + 1 >= 0 && t_out + 1 < ol) acc1 += fast_tanh(y1);
            if (t_out + 2 >= 0 && t_out + 2 < ol) acc2 += fast_tanh(y2);
            if (t_out + 3 >= 0 && t_out + 3 < ol) acc3 += fast_tanh(y3);
        }
    }

    // ---- single coalesced store per output ----
    const int o = o0 + a;
    if (o + 3 < Dn) {
        *(float4*)&out[o] = make_float4(acc0, acc1, acc2, acc3);
    } else {
        if (o + 0 < Dn) out[o + 0] = acc0;
        if (o + 1 < Dn) out[o + 1] = acc1;
        if (o + 2 < Dn) out[o + 2] = acc2;
        if (o + 3 < Dn) out[o + 3] = acc3;
    }
}

// ---------------- launcher ----------------
extern "C" void kernel_launch(void* const* d_in, const int* in_sizes, int n_in,
                              void* d_out, int out_size, void* d_ws, size_t ws_size,
                              hipStream_t stream) {
    const float* freq    = (const float*)d_in[0];
    const float* velo    = (const float*)d_in[1];
    const float* w1      = (const float*)d_in[2];
    const float* b1      = (const float*)d_in[3];
    const float* w2      = (const float*)d_in[4];
    const float* b2      = (const float*)d_in[5];
    const float* ws1     = (const float*)d_in[6];
    const float* bs1     = (const float*)d_in[7];
    const float* ws2     = (const float*)d_in[8];
    const float* bs2     = (const float*)d_in[9];
    const float* fir     = (const float*)d_in[10];
    const int*   starts  = (const int*)d_in[11];
    const int*   lengths = (const int*)d_in[12];

    const int N  = in_sizes[0];
    const int Dn = out_size;
    float* out = (float*)d_out;

    // workspace layout: amps[N*8] | outlen[N] | veln[N]
    float* amps   = (float*)d_ws;
    int*   outlen = (int*)((char*)d_ws + (size_t)N * 8 * sizeof(float));
    float* veln   = (float*)((char*)d_ws + (size_t)N * 8 * sizeof(float) + (size_t)N * sizeof(int));

    params_k<<<(N + 255) / 256, 256, 0, stream>>>(
        freq, velo, w1, b1, w2, b2, ws1, bs1, ws2, bs2,
        starts, lengths, Dn, N, amps, outlen, veln);

    int n_tiles = (Dn + TO - 1) / TO;
    synth_gather_k<<<n_tiles, 256, 0, stream>>>(
        freq, starts, amps, outlen, veln, fir, out, Dn, N);
}